// Round 7
// baseline (53.763 us; speedup 1.0000x reference)
//
#include <hip/hip_runtime.h>
#include <hip/hip_bf16.h>

// ParallelCheby2D via MFMA (layout-robust formulation, proven correct R5/R6).
// out[b,t] = Re( sum_i x[t-i] * g_i ),  g_i = sum_j C_i^T W_{4i+j} C_j,
//   C_d[q] = T_q(|x[t-d]|).
// U = M x Y per component, M[8i+p][8j+q] = w[4i+j][p][q] (32x32), K=32 via two
// v_mfma_f32_32x32x16_bf16; A and B slots (s,hi,e) both carry feature
// f = 8*(2s+hi)+e -> correct under any HW k-mapping.
// D layout (HW-measured): col=lane&31, row=(reg&3)+8*(reg>>2)+4*hi.
//
// R7 change: the per-wave weight gather from HBM (R6 diagnosis: ~16MB refetch,
// ~11us/wave serialized) is replaced by: pre-kernel f32->bf16 into d_ws once,
// per-block coalesced 4KB LDS stage, per-lane ds_read_b128 fragment assembly.

typedef __attribute__((ext_vector_type(8))) short bf16x8;   // 8 bf16 = 4 VGPRs
typedef __attribute__((ext_vector_type(16))) float f32x16;  // 16 f32 accum

static constexpr int T_LEN  = 131072;  // 2^17
static constexpr int ROUNDS = 2;       // 32 samples per wave per round
static constexpr int SPB    = 256;     // samples per block

// ---- pre-kernel: wr,wi (1024 f32 each) -> bf16 table in d_ws ----
__global__ __launch_bounds__(256) void convert_w(
    const float* __restrict__ wr, const float* __restrict__ wi,
    short* __restrict__ ws)
{
    const int k = blockIdx.x * 256 + threadIdx.x;   // 0..2047
    const float v = (k < 1024) ? wr[k] : wi[k - 1024];
    union { __hip_bfloat16 h; unsigned short u; } cv;
    cv.h = __float2bfloat16(v);                     // RNE
    ws[k] = (short)cv.u;
}

__global__ __launch_bounds__(256, 8) void cheby2d_mfma(
    const float* __restrict__ xr_g, const float* __restrict__ xi_g,
    const short* __restrict__ wbf_g,   // [2][16][8][8] bf16 (wr then wi)
    float* __restrict__ out)
{
    __shared__ short w_s[2048];            // 4 KB bf16 weight table
    __shared__ float xr_s[SPB + 4];        // [0..2] head taps, [3+s] sample s
    __shared__ float xi_s[SPB + 4];

    const int tid  = threadIdx.x;
    const int lane = tid & 63;
    const int wid  = tid >> 6;
    const int col  = lane & 31;   // sample slot / A row (8i+p)
    const int hi   = lane >> 5;   // lane half: k-half slot + Cheby row owner
    const int row  = col;

    const int base   = blockIdx.x * SPB;
    const int t_base = base & (T_LEN - 1);

    // ---- stage weights (coalesced: 256 x 16B) and x span into LDS ----
    reinterpret_cast<uint4*>(w_s)[tid] = reinterpret_cast<const uint4*>(wbf_g)[tid];
    xr_s[3 + tid] = xr_g[base + tid];
    xi_s[3 + tid] = xi_g[base + tid];
    if (tid < 3) {
        const bool head_ok = (t_base != 0);  // zero-pad at batch-row start
        xr_s[tid] = head_ok ? xr_g[base - 3 + tid] : 0.f;
        xi_s[tid] = head_ok ? xi_g[base - 3 + tid] : 0.f;
    }

    __syncthreads();

    // ---- A fragments from LDS: 4x ds_read_b128, once per wave ----
    // slot (s,hi,e) <- w[comp][4*(row>>3)+2s+hi][row&7][e]
    bf16x8 aR[2], aI[2];
#pragma unroll
    for (int s = 0; s < 2; ++s) {
        const int br = 4 * (row >> 3) + 2 * s + hi;
        aR[s] = *reinterpret_cast<const bf16x8*>(&w_s[       br * 64 + (row & 7) * 8]);
        aI[s] = *reinterpret_cast<const bf16x8*>(&w_s[1024 + br * 64 + (row & 7) * 8]);
    }

    // Persistent zero tile as C-in of each chain head.
    f32x16 zacc;
#pragma unroll
    for (int r = 0; r < 16; ++r) zacc[r] = 0.f;

#pragma unroll
    for (int rd = 0; rd < ROUNDS; ++rd) {
        const int local = (wid * ROUNDS + rd) * 32 + col;  // 0..SPB-1
        const int idx   = base + local;

        // ---- taps from LDS, magnitudes, Chebyshev rows (f32) ----
        float xr[4], xi[4], C[4][8];
#pragma unroll
        for (int d = 0; d < 4; ++d) {
            const float a = xr_s[3 + local - d];
            const float b = xi_s[3 + local - d];
            xr[d] = a; xi[d] = b;
            const float r = sqrtf(fmaf(a, a, b * b));
            C[d][0] = 1.f;
            C[d][1] = r;
            const float r2 = r + r;
#pragma unroll
            for (int q = 2; q < 8; ++q)
                C[d][q] = fmaf(r2, C[d][q - 1], -C[d][q - 2]);
        }

        // ---- B fragments, lane-local (ternary -> cndmask; RNE pack) ----
        union { short s[8]; bf16x8 v; } b0, b1;
#pragma unroll
        for (int e = 0; e < 8; ++e) {
            union { __hip_bfloat16 h; unsigned short u; } c0, c1;
            c0.h = __float2bfloat16(hi ? C[1][e] : C[0][e]);
            c1.h = __float2bfloat16(hi ? C[3][e] : C[2][e]);
            b0.s[e] = (short)c0.u;
            b1.s[e] = (short)c1.u;
        }

        // ---- U = M x Y, both components ----
        f32x16 accR = __builtin_amdgcn_mfma_f32_32x32x16_bf16(aR[0], b0.v, zacc, 0, 0, 0);
        accR        = __builtin_amdgcn_mfma_f32_32x32x16_bf16(aR[1], b1.v, accR, 0, 0, 0);
        f32x16 accI = __builtin_amdgcn_mfma_f32_32x32x16_bf16(aI[0], b0.v, zacc, 0, 0, 0);
        accI        = __builtin_amdgcn_mfma_f32_32x32x16_bf16(aI[1], b1.v, accI, 0, 0, 0);

        // ---- epilogue: acc[4i+r] = U[i][p=r+4*hi] for sample col ----
        float o = 0.f;
#pragma unroll
        for (int i = 0; i < 4; ++i) {
            float gr = 0.f, gi = 0.f;
#pragma unroll
            for (int r = 0; r < 4; ++r) {
                const float cip = hi ? C[i][4 + r] : C[i][r];
                gr = fmaf(cip, accR[4 * i + r], gr);
                gi = fmaf(cip, accI[4 * i + r], gi);
            }
            o = fmaf(xr[i], gr, o);
            o = fmaf(-xi[i], gi, o);
        }

        // Combine p-halves across lane halves; store from low half.
        o += __shfl_xor(o, 32);
        if (hi == 0) out[idx] = o;
    }
}

extern "C" void kernel_launch(void* const* d_in, const int* in_sizes, int n_in,
                              void* d_out, int out_size, void* d_ws, size_t ws_size,
                              hipStream_t stream) {
    const float* xr = (const float*)d_in[0];  // [B,1,T] float32
    const float* xi = (const float*)d_in[1];  // [B,1,T] float32
    const float* wr = (const float*)d_in[2];  // [16,8,8] float32
    const float* wi = (const float*)d_in[3];  // [16,8,8] float32
    float* out = (float*)d_out;               // [B,T] real part, float32
    short* wbf = (short*)d_ws;                // 2048 bf16 = 4 KB scratch

    convert_w<<<8, 256, 0, stream>>>(wr, wi, wbf);

    const int total  = in_sizes[0];           // 524288
    const int blocks = total / SPB;           // 2048 -> 8 waves/SIMD, 1 gen
    cheby2d_mfma<<<blocks, 256, 0, stream>>>(xr, xi, wbf, out);
}

// Round 8
// 37.558 us; speedup vs baseline: 1.4315x; 1.4315x over previous
//
#include <hip/hip_runtime.h>
#include <hip/hip_bf16.h>

// ParallelCheby2D via MFMA (layout-robust formulation, proven correct R5-R7).
// out[b,t] = Re( sum_i x[t-i] * g_i ),  g_i = sum_j C_i^T W_{4i+j} C_j,
//   C_d[q] = T_q(|x[t-d]|).
// U = M x Y per component, M[8i+p][8j+q] = w[4i+j][p][q] (32x32), K=32 via two
// v_mfma_f32_32x32x16_bf16; A and B slots (s,hi,e) both carry feature
// f = 8*(2s+hi)+e -> correct under any HW k-mapping.
// D layout (HW-measured): col=lane&31, row=(reg&3)+8*(reg>>2)+4*hi.
//
// R8: revert R7's spill (launch_bounds back to (256,2)) and pre-kernel; R5
// core + round-level software pipelining: both rounds' x-tap loads issue
// before either round's compute, so HBM latency hides under MFMA/VALU work.

typedef __attribute__((ext_vector_type(8))) short bf16x8;   // 8 bf16 = 4 VGPRs
typedef __attribute__((ext_vector_type(16))) float f32x16;  // 16 f32 accum

static constexpr int T_LEN  = 131072;  // 2^17
static constexpr int ROUNDS = 2;       // 32 samples per wave per round
static constexpr int SPB    = 256;     // samples per block = 4 waves * 2 * 32

union FragU { short s[8]; bf16x8 v; };

__device__ inline short f2bf(float f) {
    union { __hip_bfloat16 h; unsigned short u; } cv;
    cv.h = __float2bfloat16(f);   // RNE
    return (short)cv.u;
}

__global__ __launch_bounds__(256, 2) void cheby2d_mfma(
    const float* __restrict__ xr_g, const float* __restrict__ xi_g,
    const float* __restrict__ wr_g, const float* __restrict__ wi_g,
    float* __restrict__ out)
{
    const int lane = threadIdx.x & 63;
    const int gwid = (blockIdx.x * 256 + threadIdx.x) >> 6;  // global wave id
    const int col  = lane & 31;   // sample slot / A row (8i+p)
    const int hi   = lane >> 5;   // lane half: k-half slot + Cheby row owner
    const int row  = col;

    // ---- A fragments (constant weights), per-lane gather, once per wave ----
    // slot (s,hi,e) <- M[row][f=8*(2s+hi)+e] = w[4*(row>>3)+(2s+hi)][row&7][e]
    bf16x8 aR[2], aI[2];
#pragma unroll
    for (int s = 0; s < 2; ++s) {
        const int br = 4 * (row >> 3) + 2 * s + hi;
        const float* pr = wr_g + br * 64 + (row & 7) * 8;
        const float* pi = wi_g + br * 64 + (row & 7) * 8;
        FragU fr, fi;
#pragma unroll
        for (int e = 0; e < 8; ++e) { fr.s[e] = f2bf(pr[e]); fi.s[e] = f2bf(pi[e]); }
        aR[s] = fr.v; aI[s] = fi.v;
    }

    // ---- pipelined tap loads: BOTH rounds issue before any compute ----
    float xr[ROUNDS][4], xi[ROUNDS][4];
    int idx[ROUNDS];
#pragma unroll
    for (int rd = 0; rd < ROUNDS; ++rd) {
        idx[rd] = gwid * (32 * ROUNDS) + rd * 32 + col;
        const int t = idx[rd] & (T_LEN - 1);
#pragma unroll
        for (int d = 0; d < 4; ++d) {
            float a = 0.f, b = 0.f;
            if (t >= d) { a = xr_g[idx[rd] - d]; b = xi_g[idx[rd] - d]; }
            xr[rd][d] = a; xi[rd][d] = b;
        }
    }

    // Persistent zero tile as C-in of each chain head.
    f32x16 zacc;
#pragma unroll
    for (int r = 0; r < 16; ++r) zacc[r] = 0.f;

#pragma unroll
    for (int rd = 0; rd < ROUNDS; ++rd) {
        // ---- magnitudes + Chebyshev rows (f32) ----
        float C[4][8];
#pragma unroll
        for (int d = 0; d < 4; ++d) {
            const float a = xr[rd][d], b = xi[rd][d];
            const float r = sqrtf(fmaf(a, a, b * b));
            C[d][0] = 1.f;
            C[d][1] = r;
            const float r2 = r + r;
#pragma unroll
            for (int q = 2; q < 8; ++q)
                C[d][q] = fmaf(r2, C[d][q - 1], -C[d][q - 2]);
        }

        // ---- B fragments, lane-local (ternary -> cndmask; RNE pack) ----
        FragU b0, b1;
#pragma unroll
        for (int e = 0; e < 8; ++e) {
            b0.s[e] = f2bf(hi ? C[1][e] : C[0][e]);
            b1.s[e] = f2bf(hi ? C[3][e] : C[2][e]);
        }

        // ---- U = M x Y, both components (two independent 2-chains) ----
        f32x16 accR = __builtin_amdgcn_mfma_f32_32x32x16_bf16(aR[0], b0.v, zacc, 0, 0, 0);
        accR        = __builtin_amdgcn_mfma_f32_32x32x16_bf16(aR[1], b1.v, accR, 0, 0, 0);
        f32x16 accI = __builtin_amdgcn_mfma_f32_32x32x16_bf16(aI[0], b0.v, zacc, 0, 0, 0);
        accI        = __builtin_amdgcn_mfma_f32_32x32x16_bf16(aI[1], b1.v, accI, 0, 0, 0);

        // ---- epilogue: acc[4i+r] = U[i][p=r+4*hi] for sample col ----
        float o = 0.f;
#pragma unroll
        for (int i = 0; i < 4; ++i) {
            float gr = 0.f, gi = 0.f;
#pragma unroll
            for (int r = 0; r < 4; ++r) {
                const float cip = hi ? C[i][4 + r] : C[i][r];
                gr = fmaf(cip, accR[4 * i + r], gr);
                gi = fmaf(cip, accI[4 * i + r], gi);
            }
            o = fmaf(xr[rd][i], gr, o);
            o = fmaf(-xi[rd][i], gi, o);
        }

        // Combine p-halves across lane halves; store from low half.
        o += __shfl_xor(o, 32);
        if (hi == 0) out[idx[rd]] = o;
    }
}

extern "C" void kernel_launch(void* const* d_in, const int* in_sizes, int n_in,
                              void* d_out, int out_size, void* d_ws, size_t ws_size,
                              hipStream_t stream) {
    const float* xr = (const float*)d_in[0];  // [B,1,T] float32
    const float* xi = (const float*)d_in[1];  // [B,1,T] float32
    const float* wr = (const float*)d_in[2];  // [16,8,8] float32
    const float* wi = (const float*)d_in[3];  // [16,8,8] float32
    float* out = (float*)d_out;               // [B,T] real part, float32

    const int total  = in_sizes[0];           // 524288
    const int blocks = total / SPB;           // 2048
    cheby2d_mfma<<<blocks, 256, 0, stream>>>(xr, xi, wr, wi, out);
}